// Round 1
// baseline (321.899 us; speedup 1.0000x reference)
//
#include <hip/hip_runtime.h>
#include <hip/hip_bf16.h>

typedef _Float16 half8 __attribute__((ext_vector_type(8)));
typedef _Float16 half4v __attribute__((ext_vector_type(4)));
typedef float f32x4 __attribute__((ext_vector_type(4)));

constexpr int NT = 4096;   // tokens
constexpr int CH = 1024;   // channels
constexpr int NH = 16;     // heads
constexpr int HD = 64;     // head dim
constexpr int C3 = 3072;   // 3*CH

// ---------------- f32 -> f16 convert ----------------
__global__ __launch_bounds__(256) void cvt_kernel(const float* __restrict__ in,
                                                  _Float16* __restrict__ out, int n4) {
  int i = blockIdx.x * 256 + threadIdx.x;
  if (i >= n4) return;
  float4 v = ((const float4*)in)[i];
  half4v h;
  h[0] = (_Float16)v.x; h[1] = (_Float16)v.y; h[2] = (_Float16)v.z; h[3] = (_Float16)v.w;
  ((half4v*)out)[i] = h;
}

// ---------------- GEMM: C[M][Nn] = A[M][K] * Bt[Nn][K]^T ----------------
// 128x128 tile, BK=32, 4 waves, each wave 64x64 (4x4 MFMA 16x16x32 tiles).
// LDS rows padded to 40 f16 (80 B) -> 2-way bank aliasing only (free).
template <typename OutT>
__global__ __launch_bounds__(256) void gemm_bt(const _Float16* __restrict__ A,
                                               const _Float16* __restrict__ Bt,
                                               OutT* __restrict__ Cc,
                                               int M, int Nn, int K) {
  __shared__ _Float16 As[128][40];
  __shared__ _Float16 Bs[128][40];
  const int tid = threadIdx.x;
  const int lane = tid & 63, w = tid >> 6;
  const int l15 = lane & 15, l4 = lane >> 4;
  const int m0 = blockIdx.x * 128, n0 = blockIdx.y * 128;
  const int wr = w >> 1, wc = w & 1;
  f32x4 acc[4][4] = {};
  for (int k0 = 0; k0 < K; k0 += 32) {
    __syncthreads();
#pragma unroll
    for (int i = 0; i < 2; ++i) {
      int cid = tid + i * 256;          // 512 x 16B chunks per (A,B) pair
      int r = cid >> 2, cc = cid & 3;   // 4 chunks per 32-f16 row
      *(half8*)&As[r][cc * 8] = *(const half8*)(A  + (size_t)(m0 + r) * K + k0 + cc * 8);
      *(half8*)&Bs[r][cc * 8] = *(const half8*)(Bt + (size_t)(n0 + r) * K + k0 + cc * 8);
    }
    __syncthreads();
    half8 af[4], bf[4];
#pragma unroll
    for (int mt = 0; mt < 4; ++mt) af[mt] = *(half8*)&As[wr * 64 + mt * 16 + l15][l4 * 8];
#pragma unroll
    for (int nt = 0; nt < 4; ++nt) bf[nt] = *(half8*)&Bs[wc * 64 + nt * 16 + l15][l4 * 8];
#pragma unroll
    for (int mt = 0; mt < 4; ++mt)
#pragma unroll
      for (int nt = 0; nt < 4; ++nt)
        acc[mt][nt] = __builtin_amdgcn_mfma_f32_16x16x32_f16(af[mt], bf[nt], acc[mt][nt], 0, 0, 0);
  }
#pragma unroll
  for (int mt = 0; mt < 4; ++mt)
#pragma unroll
    for (int nt = 0; nt < 4; ++nt)
#pragma unroll
      for (int r = 0; r < 4; ++r) {
        int row = m0 + wr * 64 + mt * 16 + l4 * 4 + r;
        int col = n0 + wc * 64 + nt * 16 + l15;
        Cc[(size_t)row * Nn + col] = (OutT)acc[mt][nt][r];
      }
}

// ---------------- fused RMSNorm + RoPE for Q,K ----------------
// one wave per (n, h); lane = d. Q written pre-scaled by 1/sqrt(HD)=0.125.
__global__ __launch_bounds__(256) void rmsrope_kernel(const _Float16* __restrict__ qkv,
                                                      const int* __restrict__ coords,
                                                      const float* __restrict__ gq,
                                                      const float* __restrict__ gk,
                                                      _Float16* __restrict__ Qh,
                                                      _Float16* __restrict__ Kh) {
  int gw = blockIdx.x * 4 + (threadIdx.x >> 6);
  int lane = threadIdx.x & 63;
  int n = gw >> 4, h = gw & 15;
  float q = (float)qkv[(size_t)n * C3 + h * HD + lane];
  float k = (float)qkv[(size_t)n * C3 + CH + h * HD + lane];
  float sq = q * q, sk = k * k;
#pragma unroll
  for (int m = 1; m < 64; m <<= 1) { sq += __shfl_xor(sq, m); sk += __shfl_xor(sk, m); }
  q *= 8.0f / fmaxf(sqrtf(sq), 1e-12f) * gq[h * HD + lane];
  k *= 8.0f / fmaxf(sqrtf(sk), 1e-12f) * gk[h * HD + lane];
  int j = lane >> 1, p = j >> 3, dr = j & 7;
  // freq = 10000^(-dr/64) = exp(-dr * ln(1e4)/64)
  float ang = (float)coords[n * 5 + 1 + p] * __expf(-(float)dr * 0.14391157f);
  float cs = cosf(ang), sn = sinf(ang);
  float qp = __shfl_xor(q, 1), kp = __shfl_xor(k, 1);
  float qr, kr;
  if ((lane & 1) == 0) { qr = q * cs - qp * sn; kr = k * cs - kp * sn; }
  else                 { qr = qp * sn + q * cs; kr = kp * sn + k * cs; }
  size_t o = ((size_t)h * NT + n) * HD + lane;
  Qh[o] = (_Float16)(qr * 0.125f);
  Kh[o] = (_Float16)kr;
}

// ---------------- V transpose: VT[h][d][n] = qkv[n][2C + h*64 + d] ----------------
__global__ __launch_bounds__(256) void vtrans_kernel(const _Float16* __restrict__ qkv,
                                                     _Float16* __restrict__ VT) {
  __shared__ _Float16 L[64][72];
  int h = blockIdx.y, n0 = blockIdx.x * 64, t = threadIdx.x;
#pragma unroll
  for (int i = 0; i < 2; ++i) {
    int cid = t + i * 256, r = cid >> 3, c = cid & 7;
    *(half8*)&L[r][c * 8] = *(const half8*)(qkv + (size_t)(n0 + r) * C3 + 2 * CH + h * HD + c * 8);
  }
  __syncthreads();
#pragma unroll
  for (int i = 0; i < 2; ++i) {
    int cid = t + i * 256, d = cid >> 3, c = cid & 7;
    half8 v;
#pragma unroll
    for (int jj = 0; jj < 8; ++jj) v[jj] = L[c * 8 + jj][d];
    *(half8*)(VT + ((size_t)h * HD + d) * NT + n0 + c * 8) = v;
  }
}

// ---------------- flash attention, one block = (head, 64-row Q tile) ----------------
__global__ __launch_bounds__(256) void attn_kernel(const _Float16* __restrict__ Qh,
                                                   const _Float16* __restrict__ Kh,
                                                   const _Float16* __restrict__ VT,
                                                   _Float16* __restrict__ Oh) {
  __shared__ _Float16 Ks[64][72];  // [key][d]   rows 144B (16B-aligned, 2-way banks)
  __shared__ _Float16 Vs[64][72];  // [d][key]
  __shared__ _Float16 Ps[64][72];  // [q][key]
  const int tid = threadIdx.x, lane = tid & 63, w = tid >> 6;
  const int l15 = lane & 15, l4 = lane >> 4;
  // XCD-aware mapping: blocks of one head land on one XCD (8 XCDs, 2 heads each)
  int bid = blockIdx.x;
  int s = bid >> 3;
  int h = (bid & 7) * 2 + (s >> 6);
  int n0 = (s & 63) * 64;
  half8 qf[2];  // Q a-frags, rows w*16+l15 (Q already scaled by 1/8)
#pragma unroll
  for (int kk = 0; kk < 2; ++kk)
    qf[kk] = *(const half8*)(Qh + ((size_t)h * NT + n0 + w * 16 + l15) * HD + kk * 32 + l4 * 8);
  float m_r[4], l_r[4];
  f32x4 acc[4] = {};
#pragma unroll
  for (int r = 0; r < 4; ++r) { m_r[r] = -1e30f; l_r[r] = 0.0f; }
  for (int k0 = 0; k0 < NT; k0 += 64) {
    __syncthreads();
#pragma unroll
    for (int i = 0; i < 2; ++i) {
      int cid = tid + i * 256, r = cid >> 3, c = cid & 7;
      *(half8*)&Ks[r][c * 8] = *(const half8*)(Kh + ((size_t)h * NT + k0 + r) * HD + c * 8);
      *(half8*)&Vs[r][c * 8] = *(const half8*)(VT + ((size_t)h * HD + r) * NT + k0 + c * 8);
    }
    __syncthreads();
    // S strip 16x64 per wave: S[q][key], 4 key tiles x (K=64 -> 2 mfma)
    f32x4 sv[4] = {};
#pragma unroll
    for (int t = 0; t < 4; ++t)
#pragma unroll
      for (int kk = 0; kk < 2; ++kk) {
        half8 bf = *(half8*)&Ks[t * 16 + l15][kk * 32 + l4 * 8];
        sv[t] = __builtin_amdgcn_mfma_f32_16x16x32_f16(qf[kk], bf, sv[t], 0, 0, 0);
      }
    // online softmax; row = l4*4+r lives in the 16-lane (l15) shuffle group
#pragma unroll
    for (int r = 0; r < 4; ++r) {
      float mx = fmaxf(fmaxf(sv[0][r], sv[1][r]), fmaxf(sv[2][r], sv[3][r]));
      mx = fmaxf(mx, __shfl_xor(mx, 1));
      mx = fmaxf(mx, __shfl_xor(mx, 2));
      mx = fmaxf(mx, __shfl_xor(mx, 4));
      mx = fmaxf(mx, __shfl_xor(mx, 8));
      float mn = fmaxf(m_r[r], mx);
      float corr = __expf(m_r[r] - mn);
      m_r[r] = mn;
      float rs = 0.0f;
#pragma unroll
      for (int t = 0; t < 4; ++t) { float p = __expf(sv[t][r] - mn); sv[t][r] = p; rs += p; }
      rs += __shfl_xor(rs, 1); rs += __shfl_xor(rs, 2);
      rs += __shfl_xor(rs, 4); rs += __shfl_xor(rs, 8);
      l_r[r] = l_r[r] * corr + rs;
      acc[0][r] *= corr; acc[1][r] *= corr; acc[2][r] *= corr; acc[3][r] *= corr;
    }
    // P -> LDS (own 16 rows only; within-wave RAW, LDS ops are in program order)
#pragma unroll
    for (int t = 0; t < 4; ++t)
#pragma unroll
      for (int r = 0; r < 4; ++r)
        Ps[w * 16 + l4 * 4 + r][t * 16 + l15] = (_Float16)sv[t][r];
    half8 pf[2];
#pragma unroll
    for (int kk = 0; kk < 2; ++kk)
      pf[kk] = *(half8*)&Ps[w * 16 + l15][kk * 32 + l4 * 8];
    // O += P @ V : B-operand from transposed Vs (contiguous b128 reads)
#pragma unroll
    for (int t = 0; t < 4; ++t)
#pragma unroll
      for (int kk = 0; kk < 2; ++kk) {
        half8 vf = *(half8*)&Vs[t * 16 + l15][kk * 32 + l4 * 8];
        acc[t] = __builtin_amdgcn_mfma_f32_16x16x32_f16(pf[kk], vf, acc[t], 0, 0, 0);
      }
  }
#pragma unroll
  for (int t = 0; t < 4; ++t)
#pragma unroll
    for (int r = 0; r < 4; ++r) {
      int row = n0 + w * 16 + l4 * 4 + r;
      Oh[(size_t)row * CH + h * HD + t * 16 + l15] = (_Float16)(acc[t][r] / l_r[r]);
    }
}

extern "C" void kernel_launch(void* const* d_in, const int* in_sizes, int n_in,
                              void* d_out, int out_size, void* d_ws, size_t ws_size,
                              hipStream_t stream) {
  const float* x      = (const float*)d_in[0];
  const int*   coords = (const int*)d_in[1];
  const float* w_qkv  = (const float*)d_in[2];
  const float* w_out  = (const float*)d_in[3];
  const float* gq     = (const float*)d_in[4];
  const float* gk     = (const float*)d_in[5];
  float* out = (float*)d_out;

  char* ws = (char*)d_ws;
  size_t off = 0;
  auto alloc = [&](size_t bytes) { char* p = ws + off; off += bytes; return p; };
  _Float16* xh   = (_Float16*)alloc((size_t)NT * CH * 2);  // x in f16
  _Float16* wqh  = (_Float16*)alloc((size_t)C3 * CH * 2);  // w_qkv f16
  _Float16* woh  = (_Float16*)alloc((size_t)CH * CH * 2);  // w_out f16
  _Float16* qkvh = (_Float16*)alloc((size_t)NT * C3 * 2);  // qkv f16
  _Float16* Qh   = (_Float16*)alloc((size_t)NT * CH * 2);  // [H][N][64], pre-scaled
  _Float16* Kh   = (_Float16*)alloc((size_t)NT * CH * 2);  // [H][N][64]
  _Float16* VTh  = (_Float16*)alloc((size_t)NT * CH * 2);  // [H][64][N]
  _Float16* Oh   = (_Float16*)alloc((size_t)NT * CH * 2);  // attn out [N][C]
  if (off > ws_size) return;  // workspace too small: fail cleanly

  cvt_kernel<<<NT * CH / 4 / 256, 256, 0, stream>>>(x, xh, NT * CH / 4);
  cvt_kernel<<<C3 * CH / 4 / 256, 256, 0, stream>>>(w_qkv, wqh, C3 * CH / 4);
  cvt_kernel<<<CH * CH / 4 / 256, 256, 0, stream>>>(w_out, woh, CH * CH / 4);
  gemm_bt<_Float16><<<dim3(NT / 128, C3 / 128), 256, 0, stream>>>(xh, wqh, qkvh, NT, C3, CH);
  rmsrope_kernel<<<NT * NH / 4, 256, 0, stream>>>(qkvh, coords, gq, gk, Qh, Kh);
  vtrans_kernel<<<dim3(NT / 64, NH), 256, 0, stream>>>(qkvh, VTh);
  attn_kernel<<<NH * (NT / 64), 256, 0, stream>>>(Qh, Kh, VTh, Oh);
  gemm_bt<float><<<dim3(NT / 128, CH / 128), 256, 0, stream>>>(Oh, woh, out, NT, CH, CH);
}

// Round 2
// 243.503 us; speedup vs baseline: 1.3219x; 1.3219x over previous
//
#include <hip/hip_runtime.h>
#include <hip/hip_bf16.h>

typedef _Float16 half8 __attribute__((ext_vector_type(8)));
typedef _Float16 half4v __attribute__((ext_vector_type(4)));
typedef float f32x4 __attribute__((ext_vector_type(4)));

constexpr int NT = 4096;   // tokens
constexpr int CH = 1024;   // channels
constexpr int NH = 16;     // heads
constexpr int HD = 64;     // head dim
constexpr int C3 = 3072;   // 3*CH

// ---------------- f32 -> f16 convert ----------------
__global__ __launch_bounds__(256) void cvt_kernel(const float* __restrict__ in,
                                                  _Float16* __restrict__ out, int n4) {
  int i = blockIdx.x * 256 + threadIdx.x;
  if (i >= n4) return;
  float4 v = ((const float4*)in)[i];
  half4v h;
  h[0] = (_Float16)v.x; h[1] = (_Float16)v.y; h[2] = (_Float16)v.z; h[3] = (_Float16)v.w;
  ((half4v*)out)[i] = h;
}

// ---------------- GEMM: C[M][Nn] = A[M][K] * Bt[Nn][K]^T ----------------
// 128x128 tile, BK=32, 4 waves, each wave 64x64 (4x4 MFMA 16x16x32 tiles).
// LDS rows padded to 40 f16 (80 B) -> 2-way bank aliasing only (free).
template <typename OutT>
__global__ __launch_bounds__(256) void gemm_bt(const _Float16* __restrict__ A,
                                               const _Float16* __restrict__ Bt,
                                               OutT* __restrict__ Cc,
                                               int M, int Nn, int K) {
  __shared__ _Float16 As[128][40];
  __shared__ _Float16 Bs[128][40];
  const int tid = threadIdx.x;
  const int lane = tid & 63, w = tid >> 6;
  const int l15 = lane & 15, l4 = lane >> 4;
  const int m0 = blockIdx.x * 128, n0 = blockIdx.y * 128;
  const int wr = w >> 1, wc = w & 1;
  f32x4 acc[4][4] = {};
  for (int k0 = 0; k0 < K; k0 += 32) {
    __syncthreads();
#pragma unroll
    for (int i = 0; i < 2; ++i) {
      int cid = tid + i * 256;          // 512 x 16B chunks per (A,B) pair
      int r = cid >> 2, cc = cid & 3;   // 4 chunks per 32-f16 row
      *(half8*)&As[r][cc * 8] = *(const half8*)(A  + (size_t)(m0 + r) * K + k0 + cc * 8);
      *(half8*)&Bs[r][cc * 8] = *(const half8*)(Bt + (size_t)(n0 + r) * K + k0 + cc * 8);
    }
    __syncthreads();
    half8 af[4], bf[4];
#pragma unroll
    for (int mt = 0; mt < 4; ++mt) af[mt] = *(half8*)&As[wr * 64 + mt * 16 + l15][l4 * 8];
#pragma unroll
    for (int nt = 0; nt < 4; ++nt) bf[nt] = *(half8*)&Bs[wc * 64 + nt * 16 + l15][l4 * 8];
#pragma unroll
    for (int mt = 0; mt < 4; ++mt)
#pragma unroll
      for (int nt = 0; nt < 4; ++nt)
        acc[mt][nt] = __builtin_amdgcn_mfma_f32_16x16x32_f16(af[mt], bf[nt], acc[mt][nt], 0, 0, 0);
  }
#pragma unroll
  for (int mt = 0; mt < 4; ++mt)
#pragma unroll
    for (int nt = 0; nt < 4; ++nt)
#pragma unroll
      for (int r = 0; r < 4; ++r) {
        int row = m0 + wr * 64 + mt * 16 + l4 * 4 + r;
        int col = n0 + wc * 64 + nt * 16 + l15;
        Cc[(size_t)row * Nn + col] = (OutT)acc[mt][nt][r];
      }
}

// ---------------- fused RMSNorm + RoPE for Q,K ----------------
// one wave per (n, h); lane = d. Q written pre-scaled by 1/sqrt(HD)=0.125.
__global__ __launch_bounds__(256) void rmsrope_kernel(const _Float16* __restrict__ qkv,
                                                      const int* __restrict__ coords,
                                                      const float* __restrict__ gq,
                                                      const float* __restrict__ gk,
                                                      _Float16* __restrict__ Qh,
                                                      _Float16* __restrict__ Kh) {
  int gw = blockIdx.x * 4 + (threadIdx.x >> 6);
  int lane = threadIdx.x & 63;
  int n = gw >> 4, h = gw & 15;
  float q = (float)qkv[(size_t)n * C3 + h * HD + lane];
  float k = (float)qkv[(size_t)n * C3 + CH + h * HD + lane];
  float sq = q * q, sk = k * k;
#pragma unroll
  for (int m = 1; m < 64; m <<= 1) { sq += __shfl_xor(sq, m); sk += __shfl_xor(sk, m); }
  q *= 8.0f / fmaxf(sqrtf(sq), 1e-12f) * gq[h * HD + lane];
  k *= 8.0f / fmaxf(sqrtf(sk), 1e-12f) * gk[h * HD + lane];
  int j = lane >> 1, p = j >> 3, dr = j & 7;
  // freq = 10000^(-dr/64) = exp(-dr * ln(1e4)/64)
  float ang = (float)coords[n * 5 + 1 + p] * __expf(-(float)dr * 0.14391157f);
  float cs = cosf(ang), sn = sinf(ang);
  float qp = __shfl_xor(q, 1), kp = __shfl_xor(k, 1);
  float qr, kr;
  if ((lane & 1) == 0) { qr = q * cs - qp * sn; kr = k * cs - kp * sn; }
  else                 { qr = qp * sn + q * cs; kr = kp * sn + k * cs; }
  size_t o = ((size_t)h * NT + n) * HD + lane;
  Qh[o] = (_Float16)(qr * 0.125f);
  Kh[o] = (_Float16)kr;
}

// ---------------- V transpose: VT[h][d][n] = qkv[n][2C + h*64 + d] ----------------
__global__ __launch_bounds__(256) void vtrans_kernel(const _Float16* __restrict__ qkv,
                                                     _Float16* __restrict__ VT) {
  __shared__ _Float16 L[64][72];
  int h = blockIdx.y, n0 = blockIdx.x * 64, t = threadIdx.x;
#pragma unroll
  for (int i = 0; i < 2; ++i) {
    int cid = t + i * 256, r = cid >> 3, c = cid & 7;
    *(half8*)&L[r][c * 8] = *(const half8*)(qkv + (size_t)(n0 + r) * C3 + 2 * CH + h * HD + c * 8);
  }
  __syncthreads();
#pragma unroll
  for (int i = 0; i < 2; ++i) {
    int cid = t + i * 256, d = cid >> 3, c = cid & 7;
    half8 v;
#pragma unroll
    for (int jj = 0; jj < 8; ++jj) v[jj] = L[c * 8 + jj][d];
    *(half8*)(VT + ((size_t)h * HD + d) * NT + n0 + c * 8) = v;
  }
}

// ---------------- flash attention, one block = (head, 64-row Q tile) ----------------
// Scores are bounded: ||q||=||k||=8 after RMSNorm, scale 1/8 => |S| <= 8.
// exp(S) <= e^8 ~ 2981 fits f32/f16 easily -> NO max tracking, NO rescale.
__global__ __launch_bounds__(256) void attn_kernel(const _Float16* __restrict__ Qh,
                                                   const _Float16* __restrict__ Kh,
                                                   const _Float16* __restrict__ VT,
                                                   _Float16* __restrict__ Oh) {
  __shared__ _Float16 Ks[64][72];  // [key][d]
  __shared__ _Float16 Vs[64][72];  // [d][key]
  __shared__ _Float16 Ps[64][72];  // [q][key]
  const int tid = threadIdx.x, lane = tid & 63, w = tid >> 6;
  const int l15 = lane & 15, l4 = lane >> 4;
  // XCD-aware mapping: blocks of one head land on one XCD (8 XCDs, 2 heads each)
  int bid = blockIdx.x;
  int s = bid >> 3;
  int h = (bid & 7) * 2 + (s >> 6);
  int n0 = (s & 63) * 64;
  half8 qf[2];  // Q a-frags, rows w*16+l15 (Q already scaled by 1/8)
#pragma unroll
  for (int kk = 0; kk < 2; ++kk)
    qf[kk] = *(const half8*)(Qh + ((size_t)h * NT + n0 + w * 16 + l15) * HD + kk * 32 + l4 * 8);
  float lsum[4] = {0.0f, 0.0f, 0.0f, 0.0f};
  f32x4 acc[4] = {};
  for (int k0 = 0; k0 < NT; k0 += 64) {
    __syncthreads();
#pragma unroll
    for (int i = 0; i < 2; ++i) {
      int cid = tid + i * 256, r = cid >> 3, c = cid & 7;
      *(half8*)&Ks[r][c * 8] = *(const half8*)(Kh + ((size_t)h * NT + k0 + r) * HD + c * 8);
      *(half8*)&Vs[r][c * 8] = *(const half8*)(VT + ((size_t)h * HD + r) * NT + k0 + c * 8);
    }
    __syncthreads();
    // S strip 16x64 per wave: S[q][key], 4 key tiles x (K=64 -> 2 mfma)
    f32x4 sv[4] = {};
#pragma unroll
    for (int t = 0; t < 4; ++t)
#pragma unroll
      for (int kk = 0; kk < 2; ++kk) {
        half8 bf = *(half8*)&Ks[t * 16 + l15][kk * 32 + l4 * 8];
        sv[t] = __builtin_amdgcn_mfma_f32_16x16x32_f16(qf[kk], bf, sv[t], 0, 0, 0);
      }
    // bounded-score softmax: p = exp(s) directly; accumulate row sums in-register
#pragma unroll
    for (int t = 0; t < 4; ++t)
#pragma unroll
      for (int r = 0; r < 4; ++r) {
        float p = __expf(sv[t][r]);
        lsum[r] += p;
        Ps[w * 16 + l4 * 4 + r][t * 16 + l15] = (_Float16)p;
      }
    half8 pf[2];
#pragma unroll
    for (int kk = 0; kk < 2; ++kk)
      pf[kk] = *(half8*)&Ps[w * 16 + l15][kk * 32 + l4 * 8];
    // O += P @ V : B-operand from transposed Vs (contiguous b128 reads)
#pragma unroll
    for (int t = 0; t < 4; ++t)
#pragma unroll
      for (int kk = 0; kk < 2; ++kk) {
        half8 vf = *(half8*)&Vs[t * 16 + l15][kk * 32 + l4 * 8];
        acc[t] = __builtin_amdgcn_mfma_f32_16x16x32_f16(pf[kk], vf, acc[t], 0, 0, 0);
      }
  }
  // one final row-sum reduction across the 16-lane (l15) group
#pragma unroll
  for (int r = 0; r < 4; ++r) {
    lsum[r] += __shfl_xor(lsum[r], 1);
    lsum[r] += __shfl_xor(lsum[r], 2);
    lsum[r] += __shfl_xor(lsum[r], 4);
    lsum[r] += __shfl_xor(lsum[r], 8);
  }
#pragma unroll
  for (int t = 0; t < 4; ++t)
#pragma unroll
    for (int r = 0; r < 4; ++r) {
      int row = n0 + w * 16 + l4 * 4 + r;
      Oh[(size_t)row * CH + h * HD + t * 16 + l15] = (_Float16)(acc[t][r] / lsum[r]);
    }
}

extern "C" void kernel_launch(void* const* d_in, const int* in_sizes, int n_in,
                              void* d_out, int out_size, void* d_ws, size_t ws_size,
                              hipStream_t stream) {
  const float* x      = (const float*)d_in[0];
  const int*   coords = (const int*)d_in[1];
  const float* w_qkv  = (const float*)d_in[2];
  const float* w_out  = (const float*)d_in[3];
  const float* gq     = (const float*)d_in[4];
  const float* gk     = (const float*)d_in[5];
  float* out = (float*)d_out;

  char* ws = (char*)d_ws;
  size_t off = 0;
  auto alloc = [&](size_t bytes) { char* p = ws + off; off += bytes; return p; };
  _Float16* xh   = (_Float16*)alloc((size_t)NT * CH * 2);  // x in f16
  _Float16* wqh  = (_Float16*)alloc((size_t)C3 * CH * 2);  // w_qkv f16
  _Float16* woh  = (_Float16*)alloc((size_t)CH * CH * 2);  // w_out f16
  _Float16* qkvh = (_Float16*)alloc((size_t)NT * C3 * 2);  // qkv f16
  _Float16* Qh   = (_Float16*)alloc((size_t)NT * CH * 2);  // [H][N][64], pre-scaled
  _Float16* Kh   = (_Float16*)alloc((size_t)NT * CH * 2);  // [H][N][64]
  _Float16* VTh  = (_Float16*)alloc((size_t)NT * CH * 2);  // [H][64][N]
  _Float16* Oh   = (_Float16*)alloc((size_t)NT * CH * 2);  // attn out [N][C]
  if (off > ws_size) return;  // workspace too small: fail cleanly

  cvt_kernel<<<NT * CH / 4 / 256, 256, 0, stream>>>(x, xh, NT * CH / 4);
  cvt_kernel<<<C3 * CH / 4 / 256, 256, 0, stream>>>(w_qkv, wqh, C3 * CH / 4);
  cvt_kernel<<<CH * CH / 4 / 256, 256, 0, stream>>>(w_out, woh, CH * CH / 4);
  gemm_bt<_Float16><<<dim3(NT / 128, C3 / 128), 256, 0, stream>>>(xh, wqh, qkvh, NT, C3, CH);
  rmsrope_kernel<<<NT * NH / 4, 256, 0, stream>>>(qkvh, coords, gq, gk, Qh, Kh);
  vtrans_kernel<<<dim3(NT / 64, NH), 256, 0, stream>>>(qkvh, VTh);
  attn_kernel<<<NH * (NT / 64), 256, 0, stream>>>(Qh, Kh, VTh, Oh);
  gemm_bt<float><<<dim3(NT / 128, CH / 128), 256, 0, stream>>>(Oh, woh, out, NT, CH, CH);
}

// Round 5
// 229.153 us; speedup vs baseline: 1.4047x; 1.0626x over previous
//
#include <hip/hip_runtime.h>
#include <hip/hip_bf16.h>

typedef _Float16 half8 __attribute__((ext_vector_type(8)));
typedef _Float16 half4v __attribute__((ext_vector_type(4)));
typedef float f32x4 __attribute__((ext_vector_type(4)));

constexpr int NT = 4096;   // tokens
constexpr int CH = 1024;   // channels
constexpr int NH = 16;     // heads
constexpr int HD = 64;     // head dim
constexpr int C3 = 3072;   // 3*CH

// ---------------- f32 -> f16 convert ----------------
__global__ __launch_bounds__(256) void cvt_kernel(const float* __restrict__ in,
                                                  _Float16* __restrict__ out, int n4) {
  int i = blockIdx.x * 256 + threadIdx.x;
  if (i >= n4) return;
  float4 v = ((const float4*)in)[i];
  half4v h;
  h[0] = (_Float16)v.x; h[1] = (_Float16)v.y; h[2] = (_Float16)v.z; h[3] = (_Float16)v.w;
  ((half4v*)out)[i] = h;
}

// ---------------- GEMM: C[M][Nn] = A[M][K] * Bt[Nn][K]^T ----------------
template <typename OutT>
__global__ __launch_bounds__(256) void gemm_bt(const _Float16* __restrict__ A,
                                               const _Float16* __restrict__ Bt,
                                               OutT* __restrict__ Cc,
                                               int M, int Nn, int K) {
  __shared__ _Float16 As[128][40];
  __shared__ _Float16 Bs[128][40];
  const int tid = threadIdx.x;
  const int lane = tid & 63, w = tid >> 6;
  const int l15 = lane & 15, l4 = lane >> 4;
  const int m0 = blockIdx.x * 128, n0 = blockIdx.y * 128;
  const int wr = w >> 1, wc = w & 1;
  f32x4 acc[4][4] = {};
  for (int k0 = 0; k0 < K; k0 += 32) {
    __syncthreads();
#pragma unroll
    for (int i = 0; i < 2; ++i) {
      int cid = tid + i * 256;          // 512 x 16B chunks per (A,B) pair
      int r = cid >> 2, cc = cid & 3;   // 4 chunks per 32-f16 row
      *(half8*)&As[r][cc * 8] = *(const half8*)(A  + (size_t)(m0 + r) * K + k0 + cc * 8);
      *(half8*)&Bs[r][cc * 8] = *(const half8*)(Bt + (size_t)(n0 + r) * K + k0 + cc * 8);
    }
    __syncthreads();
    half8 af[4], bf[4];
#pragma unroll
    for (int mt = 0; mt < 4; ++mt) af[mt] = *(half8*)&As[wr * 64 + mt * 16 + l15][l4 * 8];
#pragma unroll
    for (int nt = 0; nt < 4; ++nt) bf[nt] = *(half8*)&Bs[wc * 64 + nt * 16 + l15][l4 * 8];
#pragma unroll
    for (int mt = 0; mt < 4; ++mt)
#pragma unroll
      for (int nt = 0; nt < 4; ++nt)
        acc[mt][nt] = __builtin_amdgcn_mfma_f32_16x16x32_f16(af[mt], bf[nt], acc[mt][nt], 0, 0, 0);
  }
#pragma unroll
  for (int mt = 0; mt < 4; ++mt)
#pragma unroll
    for (int nt = 0; nt < 4; ++nt)
#pragma unroll
      for (int r = 0; r < 4; ++r) {
        int row = m0 + wr * 64 + mt * 16 + l4 * 4 + r;
        int col = n0 + wc * 64 + nt * 16 + l15;
        Cc[(size_t)row * Nn + col] = (OutT)acc[mt][nt][r];
      }
}

// ---------------- fused RMSNorm + RoPE for Q,K ----------------
// one wave per (n, h); lane = d.
// Q pre-scaled by (1/sqrt(HD)) * log2(e) so attention uses exp2 directly.
__global__ __launch_bounds__(256) void rmsrope_kernel(const _Float16* __restrict__ qkv,
                                                      const int* __restrict__ coords,
                                                      const float* __restrict__ gq,
                                                      const float* __restrict__ gk,
                                                      _Float16* __restrict__ Qh,
                                                      _Float16* __restrict__ Kh) {
  int gw = blockIdx.x * 4 + (threadIdx.x >> 6);
  int lane = threadIdx.x & 63;
  int n = gw >> 4, h = gw & 15;
  float q = (float)qkv[(size_t)n * C3 + h * HD + lane];
  float k = (float)qkv[(size_t)n * C3 + CH + h * HD + lane];
  float sq = q * q, sk = k * k;
#pragma unroll
  for (int m = 1; m < 64; m <<= 1) { sq += __shfl_xor(sq, m); sk += __shfl_xor(sk, m); }
  q *= 8.0f / fmaxf(sqrtf(sq), 1e-12f) * gq[h * HD + lane];
  k *= 8.0f / fmaxf(sqrtf(sk), 1e-12f) * gk[h * HD + lane];
  int j = lane >> 1, p = j >> 3, dr = j & 7;
  // freq = 10000^(-dr/64) = exp(-dr * ln(1e4)/64)
  float ang = (float)coords[n * 5 + 1 + p] * __expf(-(float)dr * 0.14391157f);
  float cs = cosf(ang), sn = sinf(ang);
  float qp = __shfl_xor(q, 1), kp = __shfl_xor(k, 1);
  float qr, kr;
  if ((lane & 1) == 0) { qr = q * cs - qp * sn; kr = k * cs - kp * sn; }
  else                 { qr = qp * sn + q * cs; kr = kp * sn + k * cs; }
  size_t o = ((size_t)h * NT + n) * HD + lane;
  Qh[o] = (_Float16)(qr * 0.18033688f);   // 0.125 * log2(e)
  Kh[o] = (_Float16)kr;
}

// ---------------- V transpose: VT[h][d][n] = qkv[n][2C + h*64 + d] ----------------
__global__ __launch_bounds__(256) void vtrans_kernel(const _Float16* __restrict__ qkv,
                                                     _Float16* __restrict__ VT) {
  __shared__ _Float16 L[64][72];
  int h = blockIdx.y, n0 = blockIdx.x * 64, t = threadIdx.x;
#pragma unroll
  for (int i = 0; i < 2; ++i) {
    int cid = t + i * 256, r = cid >> 3, c = cid & 7;
    *(half8*)&L[r][c * 8] = *(const half8*)(qkv + (size_t)(n0 + r) * C3 + 2 * CH + h * HD + c * 8);
  }
  __syncthreads();
#pragma unroll
  for (int i = 0; i < 2; ++i) {
    int cid = t + i * 256, d = cid >> 3, c = cid & 7;
    half8 v;
#pragma unroll
    for (int jj = 0; jj < 8; ++jj) v[jj] = L[c * 8 + jj][d];
    *(half8*)(VT + ((size_t)h * HD + d) * NT + n0 + c * 8) = v;
  }
}

// ---------------- flash attention, one block = (head, 64-row Q tile) ----------------
// Bounded scores (|S|<=8 by RMSNorm + Cauchy-Schwarz) -> no max tracking.
// Swapped QK^T: sv[t] = mfma(K_frag, Q_frag) puts q on the D column index
// (q = lane&15), so each lane holds 16 P-values of ONE q row -> PV A-frags are
// built from registers, no P LDS round-trip, no cross-lane softmax.
// Key-slot permutation: key kappa = 32kk+8l4+4tb+r staged at LDS row
// rho = 32kk+16tb+4l4+r so that pf[kk][j] = sv[2kk+(j>>2)][j&3].
__global__ __launch_bounds__(256) void attn_kernel(const _Float16* __restrict__ Qh,
                                                   const _Float16* __restrict__ Kh,
                                                   const _Float16* __restrict__ VT,
                                                   _Float16* __restrict__ Oh) {
  __shared__ _Float16 Ks[64][72];  // [slot][d], rows permuted by rho
  __shared__ _Float16 Vs[64][72];  // [d][key]
  const int tid = threadIdx.x, lane = tid & 63, w = tid >> 6;
  const int l15 = lane & 15, l4 = lane >> 4;
  // XCD-aware mapping: blocks of one head land on one XCD (8 XCDs, 2 heads each)
  int bid = blockIdx.x;
  int s = bid >> 3;
  int h = (bid & 7) * 2 + (s >> 6);
  int n0 = (s & 63) * 64;
  half8 qf[2];  // Q frags (rows = q), Q pre-scaled by 0.125*log2(e)
#pragma unroll
  for (int kk = 0; kk < 2; ++kk)
    qf[kk] = *(const half8*)(Qh + ((size_t)h * NT + n0 + w * 16 + l15) * HD + kk * 32 + l4 * 8);
  float lsum = 0.0f;
  f32x4 acc[4] = {};
  for (int k0 = 0; k0 < NT; k0 += 64) {
    __syncthreads();
#pragma unroll
    for (int i = 0; i < 2; ++i) {
      int cid = tid + i * 256, gr = cid >> 3, c = cid & 7;
      // rho(gr): swap the tb bit (bit2) with the l4 bits (bits3-4)
      int pr = (gr & 32) | (((gr >> 2) & 1) << 4) | (((gr >> 3) & 3) << 2) | (gr & 3);
      *(half8*)&Ks[pr][c * 8] = *(const half8*)(Kh + ((size_t)h * NT + k0 + gr) * HD + c * 8);
      *(half8*)&Vs[gr][c * 8] = *(const half8*)(VT + ((size_t)h * HD + gr) * NT + k0 + c * 8);
    }
    __syncthreads();
    // S^T strip: D[slot][q], 4 slot-tiles x (d=64 -> 2 mfma)
    f32x4 sv[4] = {};
#pragma unroll
    for (int t = 0; t < 4; ++t)
#pragma unroll
      for (int kk = 0; kk < 2; ++kk) {
        half8 kf = *(half8*)&Ks[t * 16 + l15][kk * 32 + l4 * 8];
        sv[t] = __builtin_amdgcn_mfma_f32_16x16x32_f16(kf, qf[kk], sv[t], 0, 0, 0);
      }
    // p = 2^S (Q carries log2e); build PV A-frags purely in registers
    half8 pf[2];
#pragma unroll
    for (int kk = 0; kk < 2; ++kk)
#pragma unroll
      for (int j = 0; j < 8; ++j) {
        float p = exp2f(sv[2 * kk + (j >> 2)][j & 3]);
        lsum += p;
        pf[kk][j] = (_Float16)p;
      }
    // O += P @ V : B-operand from transposed Vs (contiguous b128 reads)
#pragma unroll
    for (int t = 0; t < 4; ++t)
#pragma unroll
      for (int kk = 0; kk < 2; ++kk) {
        half8 vf = *(half8*)&Vs[t * 16 + l15][kk * 32 + l4 * 8];
        acc[t] = __builtin_amdgcn_mfma_f32_16x16x32_f16(pf[kk], vf, acc[t], 0, 0, 0);
      }
  }
  // lane-local lsum covers 16 keys of q=l15; reduce across the l4 group
  lsum += __shfl_xor(lsum, 16);
  lsum += __shfl_xor(lsum, 32);
  // move row-sums from q=l15 indexing to q=l4*4+r indexing for the epilogue
  float linv[4];
#pragma unroll
  for (int r = 0; r < 4; ++r) linv[r] = 1.0f / __shfl(lsum, l4 * 4 + r);
#pragma unroll
  for (int t = 0; t < 4; ++t)
#pragma unroll
    for (int r = 0; r < 4; ++r) {
      int row = n0 + w * 16 + l4 * 4 + r;
      Oh[(size_t)row * CH + h * HD + t * 16 + l15] = (_Float16)(acc[t][r] * linv[r]);
    }
}

extern "C" void kernel_launch(void* const* d_in, const int* in_sizes, int n_in,
                              void* d_out, int out_size, void* d_ws, size_t ws_size,
                              hipStream_t stream) {
  const float* x      = (const float*)d_in[0];
  const int*   coords = (const int*)d_in[1];
  const float* w_qkv  = (const float*)d_in[2];
  const float* w_out  = (const float*)d_in[3];
  const float* gq     = (const float*)d_in[4];
  const float* gk     = (const float*)d_in[5];
  float* out = (float*)d_out;

  char* ws = (char*)d_ws;
  size_t off = 0;
  auto alloc = [&](size_t bytes) { char* p = ws + off; off += bytes; return p; };
  _Float16* xh   = (_Float16*)alloc((size_t)NT * CH * 2);  // x in f16
  _Float16* wqh  = (_Float16*)alloc((size_t)C3 * CH * 2);  // w_qkv f16
  _Float16* woh  = (_Float16*)alloc((size_t)CH * CH * 2);  // w_out f16
  _Float16* qkvh = (_Float16*)alloc((size_t)NT * C3 * 2);  // qkv f16
  _Float16* Qh   = (_Float16*)alloc((size_t)NT * CH * 2);  // [H][N][64], pre-scaled
  _Float16* Kh   = (_Float16*)alloc((size_t)NT * CH * 2);  // [H][N][64]
  _Float16* VTh  = (_Float16*)alloc((size_t)NT * CH * 2);  // [H][64][N]
  _Float16* Oh   = (_Float16*)alloc((size_t)NT * CH * 2);  // attn out [N][C]
  if (off > ws_size) return;  // workspace too small: fail cleanly

  cvt_kernel<<<NT * CH / 4 / 256, 256, 0, stream>>>(x, xh, NT * CH / 4);
  cvt_kernel<<<C3 * CH / 4 / 256, 256, 0, stream>>>(w_qkv, wqh, C3 * CH / 4);
  cvt_kernel<<<CH * CH / 4 / 256, 256, 0, stream>>>(w_out, woh, CH * CH / 4);
  gemm_bt<_Float16><<<dim3(NT / 128, C3 / 128), 256, 0, stream>>>(xh, wqh, qkvh, NT, C3, CH);
  rmsrope_kernel<<<NT * NH / 4, 256, 0, stream>>>(qkvh, coords, gq, gk, Qh, Kh);
  vtrans_kernel<<<dim3(NT / 64, NH), 256, 0, stream>>>(qkvh, VTh);
  attn_kernel<<<NH * (NT / 64), 256, 0, stream>>>(Qh, Kh, VTh, Oh);
  gemm_bt<float><<<dim3(NT / 128, CH / 128), 256, 0, stream>>>(Oh, woh, out, NT, CH, CH);
}

// Round 6
// 203.025 us; speedup vs baseline: 1.5855x; 1.1287x over previous
//
#include <hip/hip_runtime.h>
#include <hip/hip_bf16.h>

typedef _Float16 half8 __attribute__((ext_vector_type(8)));
typedef _Float16 half4v __attribute__((ext_vector_type(4)));
typedef _Float16 half2 __attribute__((ext_vector_type(2)));
typedef float f32x4 __attribute__((ext_vector_type(4)));

constexpr int NT = 4096;   // tokens
constexpr int CH = 1024;   // channels
constexpr int NH = 16;     // heads
constexpr int HD = 64;     // head dim
constexpr int C3 = 3072;   // 3*CH

#if __has_builtin(__builtin_amdgcn_exp2f)
#define EXP2(x) __builtin_amdgcn_exp2f(x)
#else
#define EXP2(x) exp2f(x)
#endif

static __device__ inline half2 pk_f16(float a, float b) {
  auto r = __builtin_amdgcn_cvt_pkrtz(a, b);   // v_cvt_pkrtz_f16_f32
  return *(half2*)&r;
}

// ---------------- f32 -> f16 convert ----------------
__global__ __launch_bounds__(256) void cvt_kernel(const float* __restrict__ in,
                                                  _Float16* __restrict__ out, int n4) {
  int i = blockIdx.x * 256 + threadIdx.x;
  if (i >= n4) return;
  float4 v = ((const float4*)in)[i];
  half4v h;
  h[0] = (_Float16)v.x; h[1] = (_Float16)v.y; h[2] = (_Float16)v.z; h[3] = (_Float16)v.w;
  ((half4v*)out)[i] = h;
}

// ---------------- GEMM: C[M][Nn] = A[M][K] * Bt[Nn][K]^T ----------------
template <typename OutT>
__global__ __launch_bounds__(256) void gemm_bt(const _Float16* __restrict__ A,
                                               const _Float16* __restrict__ Bt,
                                               OutT* __restrict__ Cc,
                                               int M, int Nn, int K) {
  __shared__ _Float16 As[128][40];
  __shared__ _Float16 Bs[128][40];
  const int tid = threadIdx.x;
  const int lane = tid & 63, w = tid >> 6;
  const int l15 = lane & 15, l4 = lane >> 4;
  const int m0 = blockIdx.x * 128, n0 = blockIdx.y * 128;
  const int wr = w >> 1, wc = w & 1;
  f32x4 acc[4][4] = {};
  for (int k0 = 0; k0 < K; k0 += 32) {
    __syncthreads();
#pragma unroll
    for (int i = 0; i < 2; ++i) {
      int cid = tid + i * 256;          // 512 x 16B chunks per (A,B) pair
      int r = cid >> 2, cc = cid & 3;   // 4 chunks per 32-f16 row
      *(half8*)&As[r][cc * 8] = *(const half8*)(A  + (size_t)(m0 + r) * K + k0 + cc * 8);
      *(half8*)&Bs[r][cc * 8] = *(const half8*)(Bt + (size_t)(n0 + r) * K + k0 + cc * 8);
    }
    __syncthreads();
    half8 af[4], bf[4];
#pragma unroll
    for (int mt = 0; mt < 4; ++mt) af[mt] = *(half8*)&As[wr * 64 + mt * 16 + l15][l4 * 8];
#pragma unroll
    for (int nt = 0; nt < 4; ++nt) bf[nt] = *(half8*)&Bs[wc * 64 + nt * 16 + l15][l4 * 8];
#pragma unroll
    for (int mt = 0; mt < 4; ++mt)
#pragma unroll
      for (int nt = 0; nt < 4; ++nt)
        acc[mt][nt] = __builtin_amdgcn_mfma_f32_16x16x32_f16(af[mt], bf[nt], acc[mt][nt], 0, 0, 0);
  }
#pragma unroll
  for (int mt = 0; mt < 4; ++mt)
#pragma unroll
    for (int nt = 0; nt < 4; ++nt)
#pragma unroll
      for (int r = 0; r < 4; ++r) {
        int row = m0 + wr * 64 + mt * 16 + l4 * 4 + r;
        int col = n0 + wc * 64 + nt * 16 + l15;
        Cc[(size_t)row * Nn + col] = (OutT)acc[mt][nt][r];
      }
}

// ---------------- fused RMSNorm + RoPE for Q,K ----------------
// one wave per (n, h); lane = d.
// Q pre-scaled by (1/sqrt(HD)) * log2(e) so attention uses exp2 directly.
__global__ __launch_bounds__(256) void rmsrope_kernel(const _Float16* __restrict__ qkv,
                                                      const int* __restrict__ coords,
                                                      const float* __restrict__ gq,
                                                      const float* __restrict__ gk,
                                                      _Float16* __restrict__ Qh,
                                                      _Float16* __restrict__ Kh) {
  int gw = blockIdx.x * 4 + (threadIdx.x >> 6);
  int lane = threadIdx.x & 63;
  int n = gw >> 4, h = gw & 15;
  float q = (float)qkv[(size_t)n * C3 + h * HD + lane];
  float k = (float)qkv[(size_t)n * C3 + CH + h * HD + lane];
  float sq = q * q, sk = k * k;
#pragma unroll
  for (int m = 1; m < 64; m <<= 1) { sq += __shfl_xor(sq, m); sk += __shfl_xor(sk, m); }
  q *= 8.0f / fmaxf(sqrtf(sq), 1e-12f) * gq[h * HD + lane];
  k *= 8.0f / fmaxf(sqrtf(sk), 1e-12f) * gk[h * HD + lane];
  int j = lane >> 1, p = j >> 3, dr = j & 7;
  // freq = 10000^(-dr/64) = exp(-dr * ln(1e4)/64)
  float ang = (float)coords[n * 5 + 1 + p] * __expf(-(float)dr * 0.14391157f);
  float cs = cosf(ang), sn = sinf(ang);
  float qp = __shfl_xor(q, 1), kp = __shfl_xor(k, 1);
  float qr, kr;
  if ((lane & 1) == 0) { qr = q * cs - qp * sn; kr = k * cs - kp * sn; }
  else                 { qr = qp * sn + q * cs; kr = kp * sn + k * cs; }
  size_t o = ((size_t)h * NT + n) * HD + lane;
  Qh[o] = (_Float16)(qr * 0.18033688f);   // 0.125 * log2(e)
  Kh[o] = (_Float16)kr;
}

// ---------------- V transpose: VT[h][d][n] = qkv[n][2C + h*64 + d] ----------------
__global__ __launch_bounds__(256) void vtrans_kernel(const _Float16* __restrict__ qkv,
                                                     _Float16* __restrict__ VT) {
  __shared__ _Float16 L[64][72];
  int h = blockIdx.y, n0 = blockIdx.x * 64, t = threadIdx.x;
#pragma unroll
  for (int i = 0; i < 2; ++i) {
    int cid = t + i * 256, r = cid >> 3, c = cid & 7;
    *(half8*)&L[r][c * 8] = *(const half8*)(qkv + (size_t)(n0 + r) * C3 + 2 * CH + h * HD + c * 8);
  }
  __syncthreads();
#pragma unroll
  for (int i = 0; i < 2; ++i) {
    int cid = t + i * 256, d = cid >> 3, c = cid & 7;
    half8 v;
#pragma unroll
    for (int jj = 0; jj < 8; ++jj) v[jj] = L[c * 8 + jj][d];
    *(half8*)(VT + ((size_t)h * HD + d) * NT + n0 + c * 8) = v;
  }
}

// ---------------- flash attention, one block = (head, 64-row Q tile) ----------------
// Bounded scores (|S|<=8) -> no max tracking (see r2 notes).
// Swapped QK^T + key-slot permutation -> P stays in registers.
// lsum via MFMA ones-row (Vs rows 64..79, row 64 = 1.0) -> no VALU adds.
// Reg-staged ping-pong prefetch (sets A/B) -> HBM latency hidden under compute.
__global__ __launch_bounds__(256, 4) void attn_kernel(const _Float16* __restrict__ Qh,
                                                      const _Float16* __restrict__ Kh,
                                                      const _Float16* __restrict__ VT,
                                                      _Float16* __restrict__ Oh) {
  __shared__ _Float16 Ks[64][72];  // [slot][d], rows permuted by rho
  __shared__ _Float16 Vs[80][72];  // [d][key]; rows 64..79: ones-row block
  const int tid = threadIdx.x, lane = tid & 63, w = tid >> 6;
  const int l15 = lane & 15, l4 = lane >> 4;
  // XCD-aware mapping: blocks of one head land on one XCD (8 XCDs, 2 heads each)
  int bid = blockIdx.x;
  int s = bid >> 3;
  int h = (bid & 7) * 2 + (s >> 6);
  int n0 = (s & 63) * 64;
  // init ones-row block (rows 64..79 of Vs): row 64 = 1.0, rest 0
  for (int idx = tid; idx < 16 * 72; idx += 256) {
    int rr = idx / 72, cc = idx % 72;
    Vs[64 + rr][cc] = (_Float16)(rr == 0 ? 1.0f : 0.0f);
  }
  half8 qf[2];  // Q frags (rows = q), Q pre-scaled by 0.125*log2(e)
#pragma unroll
  for (int kk = 0; kk < 2; ++kk)
    qf[kk] = *(const half8*)(Qh + ((size_t)h * NT + n0 + w * 16 + l15) * HD + kk * 32 + l4 * 8);
  f32x4 acc[4] = {};
  f32x4 acc5 = {0.f, 0.f, 0.f, 0.f};   // lsum accumulator (col 0 = row-sum)
  // staging geometry: thread covers K rows {gr0, gr1} chunk c; K stored at rho(row)
  const int gr0 = tid >> 3, gr1 = gr0 + 32, c = tid & 7;
  auto rho = [](int g) {
    return (g & 32) | (((g >> 2) & 1) << 4) | (((g >> 3) & 3) << 2) | (g & 3);
  };
  const int pr0 = rho(gr0), pr1 = rho(gr1);
  const _Float16* Kb = Kh + (size_t)h * NT * HD;
  const _Float16* Vb = VT + (size_t)h * HD * NT;
  half8 kA0, kA1, vA0, vA1, kB0, kB1, vB0, vB1;
  auto loadset = [&](int k0, half8& ka, half8& kb, half8& va, half8& vb) {
    ka = *(const half8*)(Kb + (size_t)(k0 + gr0) * HD + c * 8);
    kb = *(const half8*)(Kb + (size_t)(k0 + gr1) * HD + c * 8);
    va = *(const half8*)(Vb + (size_t)gr0 * NT + k0 + c * 8);
    vb = *(const half8*)(Vb + (size_t)gr1 * NT + k0 + c * 8);
  };
  auto storeset = [&](half8 ka, half8 kb, half8 va, half8 vb) {
    *(half8*)&Ks[pr0][c * 8] = ka;
    *(half8*)&Ks[pr1][c * 8] = kb;
    *(half8*)&Vs[gr0][c * 8] = va;
    *(half8*)&Vs[gr1][c * 8] = vb;
  };
  auto compute = [&]() {
    f32x4 sv[4] = {};
    __builtin_amdgcn_s_setprio(1);
#pragma unroll
    for (int t = 0; t < 4; ++t) {
      half8 kf0 = *(half8*)&Ks[t * 16 + l15][l4 * 8];
      half8 kf1 = *(half8*)&Ks[t * 16 + l15][32 + l4 * 8];
      sv[t] = __builtin_amdgcn_mfma_f32_16x16x32_f16(kf0, qf[0], sv[t], 0, 0, 0);
      sv[t] = __builtin_amdgcn_mfma_f32_16x16x32_f16(kf1, qf[1], sv[t], 0, 0, 0);
    }
    __builtin_amdgcn_s_setprio(0);
    // p = 2^S; pack pairs with v_cvt_pkrtz (pf[kk][j] = e[2kk + (j>>2)][j&3])
    float e[4][4];
#pragma unroll
    for (int t = 0; t < 4; ++t)
#pragma unroll
      for (int r = 0; r < 4; ++r) e[t][r] = EXP2(sv[t][r]);
    union U { half8 v; half2 p[4]; } u0, u1;
    u0.p[0] = pk_f16(e[0][0], e[0][1]); u0.p[1] = pk_f16(e[0][2], e[0][3]);
    u0.p[2] = pk_f16(e[1][0], e[1][1]); u0.p[3] = pk_f16(e[1][2], e[1][3]);
    u1.p[0] = pk_f16(e[2][0], e[2][1]); u1.p[1] = pk_f16(e[2][2], e[2][3]);
    u1.p[2] = pk_f16(e[3][0], e[3][1]); u1.p[3] = pk_f16(e[3][2], e[3][3]);
    __builtin_amdgcn_s_setprio(1);
#pragma unroll
    for (int t = 0; t < 5; ++t) {
      half8 vf0 = *(half8*)&Vs[t * 16 + l15][l4 * 8];
      half8 vf1 = *(half8*)&Vs[t * 16 + l15][32 + l4 * 8];
      f32x4& a = (t < 4) ? acc[t] : acc5;   // t is compile-time (unrolled)
      a = __builtin_amdgcn_mfma_f32_16x16x32_f16(u0.v, vf0, a, 0, 0, 0);
      a = __builtin_amdgcn_mfma_f32_16x16x32_f16(u1.v, vf1, a, 0, 0, 0);
    }
    __builtin_amdgcn_s_setprio(0);
  };
  // prologue: tile 0 into set A
  loadset(0, kA0, kA1, vA0, vA1);
  for (int k0 = 0; k0 < NT; k0 += 128) {
    __syncthreads();                       // LDS free (prior reads done)
    storeset(kA0, kA1, vA0, vA1);
    __syncthreads();                       // LDS ready
    loadset(k0 + 64, kB0, kB1, vB0, vB1);  // prefetch next tile (always < NT)
    compute();                             // tile k0
    __syncthreads();
    storeset(kB0, kB1, vB0, vB1);
    __syncthreads();
    if (k0 + 128 < NT) loadset(k0 + 128, kA0, kA1, vA0, vA1);
    compute();                             // tile k0+64
  }
  // lsum for q-row (l4*4+r) sits in acc5[r] of lane (l4, l15=0)
  float linv[4];
#pragma unroll
  for (int r = 0; r < 4; ++r) linv[r] = 1.0f / __shfl(acc5[r], lane & 48);
#pragma unroll
  for (int t = 0; t < 4; ++t)
#pragma unroll
    for (int r = 0; r < 4; ++r) {
      int row = n0 + w * 16 + l4 * 4 + r;
      Oh[(size_t)row * CH + h * HD + t * 16 + l15] = (_Float16)(acc[t][r] * linv[r]);
    }
}

extern "C" void kernel_launch(void* const* d_in, const int* in_sizes, int n_in,
                              void* d_out, int out_size, void* d_ws, size_t ws_size,
                              hipStream_t stream) {
  const float* x      = (const float*)d_in[0];
  const int*   coords = (const int*)d_in[1];
  const float* w_qkv  = (const float*)d_in[2];
  const float* w_out  = (const float*)d_in[3];
  const float* gq     = (const float*)d_in[4];
  const float* gk     = (const float*)d_in[5];
  float* out = (float*)d_out;

  char* ws = (char*)d_ws;
  size_t off = 0;
  auto alloc = [&](size_t bytes) { char* p = ws + off; off += bytes; return p; };
  _Float16* xh   = (_Float16*)alloc((size_t)NT * CH * 2);  // x in f16
  _Float16* wqh  = (_Float16*)alloc((size_t)C3 * CH * 2);  // w_qkv f16
  _Float16* woh  = (_Float16*)alloc((size_t)CH * CH * 2);  // w_out f16
  _Float16* qkvh = (_Float16*)alloc((size_t)NT * C3 * 2);  // qkv f16
  _Float16* Qh   = (_Float16*)alloc((size_t)NT * CH * 2);  // [H][N][64], pre-scaled
  _Float16* Kh   = (_Float16*)alloc((size_t)NT * CH * 2);  // [H][N][64]
  _Float16* VTh  = (_Float16*)alloc((size_t)NT * CH * 2);  // [H][64][N]
  _Float16* Oh   = (_Float16*)alloc((size_t)NT * CH * 2);  // attn out [N][C]
  if (off > ws_size) return;  // workspace too small: fail cleanly

  cvt_kernel<<<NT * CH / 4 / 256, 256, 0, stream>>>(x, xh, NT * CH / 4);
  cvt_kernel<<<C3 * CH / 4 / 256, 256, 0, stream>>>(w_qkv, wqh, C3 * CH / 4);
  cvt_kernel<<<CH * CH / 4 / 256, 256, 0, stream>>>(w_out, woh, CH * CH / 4);
  gemm_bt<_Float16><<<dim3(NT / 128, C3 / 128), 256, 0, stream>>>(xh, wqh, qkvh, NT, C3, CH);
  rmsrope_kernel<<<NT * NH / 4, 256, 0, stream>>>(qkvh, coords, gq, gk, Qh, Kh);
  vtrans_kernel<<<dim3(NT / 64, NH), 256, 0, stream>>>(qkvh, VTh);
  attn_kernel<<<NH * (NT / 64), 256, 0, stream>>>(Qh, Kh, VTh, Oh);
  gemm_bt<float><<<dim3(NT / 128, CH / 128), 256, 0, stream>>>(Oh, woh, out, NT, CH, CH);
}

// Round 7
// 176.049 us; speedup vs baseline: 1.8285x; 1.1532x over previous
//
#include <hip/hip_runtime.h>
#include <hip/hip_bf16.h>

typedef _Float16 half8 __attribute__((ext_vector_type(8)));
typedef _Float16 half4v __attribute__((ext_vector_type(4)));
typedef _Float16 half2 __attribute__((ext_vector_type(2)));
typedef float f32x4 __attribute__((ext_vector_type(4)));

constexpr int NT = 4096;   // tokens
constexpr int CH = 1024;   // channels
constexpr int NH = 16;     // heads
constexpr int HD = 64;     // head dim
constexpr int C3 = 3072;   // 3*CH

#if __has_builtin(__builtin_amdgcn_exp2f)
#define EXP2(x) __builtin_amdgcn_exp2f(x)
#else
#define EXP2(x) exp2f(x)
#endif

#define GLOAD_LDS16(gp, lp) __builtin_amdgcn_global_load_lds( \
    (const __attribute__((address_space(1))) void*)(gp),      \
    (__attribute__((address_space(3))) void*)(lp), 16, 0, 0)

static __device__ inline half2 pk_f16(float a, float b) {
  auto r = __builtin_amdgcn_cvt_pkrtz(a, b);   // v_cvt_pkrtz_f16_f32
  return *(half2*)&r;
}

// ---------------- f32 -> f16 convert ----------------
__global__ __launch_bounds__(256) void cvt_kernel(const float* __restrict__ in,
                                                  _Float16* __restrict__ out, int n4) {
  int i = blockIdx.x * 256 + threadIdx.x;
  if (i >= n4) return;
  float4 v = ((const float4*)in)[i];
  half4v h;
  h[0] = (_Float16)v.x; h[1] = (_Float16)v.y; h[2] = (_Float16)v.z; h[3] = (_Float16)v.w;
  ((half4v*)out)[i] = h;
}

// ---------------- GEMM: C[M][Nn] = A[M][K] * Bt[Nn][K]^T ----------------
// m97 structure: 128x128 tile, BK=32, linear LDS, global_load_lds width-16
// staging (wave-uniform LDS base + lane*16; per-lane global src).
// 8-way ds_read bank conflicts accepted (m97: not critical-path at 2-barrier).
template <typename OutT>
__global__ __launch_bounds__(256) void gemm_bt(const _Float16* __restrict__ A,
                                               const _Float16* __restrict__ Bt,
                                               OutT* __restrict__ Cc,
                                               int M, int Nn, int K) {
  __shared__ _Float16 As[128][32];
  __shared__ _Float16 Bs[128][32];
  const int tid = threadIdx.x;
  const int lane = tid & 63, w = tid >> 6;
  const int l15 = lane & 15, l4 = lane >> 4;
  const int m0 = blockIdx.x * 128, n0 = blockIdx.y * 128;
  const int wr = w >> 1, wc = w & 1;
  const int rb = w * 32;           // wave's 32-row staging band
  const int rl = lane >> 2;        // row within 16-row chunk (4 lanes/row)
  const int cb = (lane & 3) * 8;   // f16 col of this lane's 16B
  f32x4 acc[4][4] = {};
  for (int k0 = 0; k0 < K; k0 += 32) {
    __syncthreads();               // prior-tile reads done (drains vmcnt too)
    GLOAD_LDS16(A  + (size_t)(m0 + rb + rl) * K + k0 + cb,      &As[rb][0]);
    GLOAD_LDS16(A  + (size_t)(m0 + rb + 16 + rl) * K + k0 + cb, &As[rb + 16][0]);
    GLOAD_LDS16(Bt + (size_t)(n0 + rb + rl) * K + k0 + cb,      &Bs[rb][0]);
    GLOAD_LDS16(Bt + (size_t)(n0 + rb + 16 + rl) * K + k0 + cb, &Bs[rb + 16][0]);
    __syncthreads();               // compiler emits vmcnt(0) drain before barrier
    half8 af[4], bf[4];
#pragma unroll
    for (int mt = 0; mt < 4; ++mt) af[mt] = *(half8*)&As[wr * 64 + mt * 16 + l15][l4 * 8];
#pragma unroll
    for (int nt = 0; nt < 4; ++nt) bf[nt] = *(half8*)&Bs[wc * 64 + nt * 16 + l15][l4 * 8];
#pragma unroll
    for (int mt = 0; mt < 4; ++mt)
#pragma unroll
      for (int nt = 0; nt < 4; ++nt)
        acc[mt][nt] = __builtin_amdgcn_mfma_f32_16x16x32_f16(af[mt], bf[nt], acc[mt][nt], 0, 0, 0);
  }
#pragma unroll
  for (int mt = 0; mt < 4; ++mt)
#pragma unroll
    for (int nt = 0; nt < 4; ++nt)
#pragma unroll
      for (int r = 0; r < 4; ++r) {
        int row = m0 + wr * 64 + mt * 16 + l4 * 4 + r;
        int col = n0 + wc * 64 + nt * 16 + l15;
        Cc[(size_t)row * Nn + col] = (OutT)acc[mt][nt][r];
      }
}

// ---------------- fused RMSNorm + RoPE for Q,K ----------------
// one wave per (n, h); lane = d.
// Q pre-scaled by (1/sqrt(HD)) * log2(e) so attention uses exp2 directly.
__global__ __launch_bounds__(256) void rmsrope_kernel(const _Float16* __restrict__ qkv,
                                                      const int* __restrict__ coords,
                                                      const float* __restrict__ gq,
                                                      const float* __restrict__ gk,
                                                      _Float16* __restrict__ Qh,
                                                      _Float16* __restrict__ Kh) {
  int gw = blockIdx.x * 4 + (threadIdx.x >> 6);
  int lane = threadIdx.x & 63;
  int n = gw >> 4, h = gw & 15;
  float q = (float)qkv[(size_t)n * C3 + h * HD + lane];
  float k = (float)qkv[(size_t)n * C3 + CH + h * HD + lane];
  float sq = q * q, sk = k * k;
#pragma unroll
  for (int m = 1; m < 64; m <<= 1) { sq += __shfl_xor(sq, m); sk += __shfl_xor(sk, m); }
  q *= 8.0f / fmaxf(sqrtf(sq), 1e-12f) * gq[h * HD + lane];
  k *= 8.0f / fmaxf(sqrtf(sk), 1e-12f) * gk[h * HD + lane];
  int j = lane >> 1, p = j >> 3, dr = j & 7;
  // freq = 10000^(-dr/64) = exp(-dr * ln(1e4)/64)
  float ang = (float)coords[n * 5 + 1 + p] * __expf(-(float)dr * 0.14391157f);
  float cs = cosf(ang), sn = sinf(ang);
  float qp = __shfl_xor(q, 1), kp = __shfl_xor(k, 1);
  float qr, kr;
  if ((lane & 1) == 0) { qr = q * cs - qp * sn; kr = k * cs - kp * sn; }
  else                 { qr = qp * sn + q * cs; kr = kp * sn + k * cs; }
  size_t o = ((size_t)h * NT + n) * HD + lane;
  Qh[o] = (_Float16)(qr * 0.18033688f);   // 0.125 * log2(e)
  Kh[o] = (_Float16)kr;
}

// ---------------- V transpose: VT[h][d][n] = qkv[n][2C + h*64 + d] ----------------
__global__ __launch_bounds__(256) void vtrans_kernel(const _Float16* __restrict__ qkv,
                                                     _Float16* __restrict__ VT) {
  __shared__ _Float16 L[64][72];
  int h = blockIdx.y, n0 = blockIdx.x * 64, t = threadIdx.x;
#pragma unroll
  for (int i = 0; i < 2; ++i) {
    int cid = t + i * 256, r = cid >> 3, c = cid & 7;
    *(half8*)&L[r][c * 8] = *(const half8*)(qkv + (size_t)(n0 + r) * C3 + 2 * CH + h * HD + c * 8);
  }
  __syncthreads();
#pragma unroll
  for (int i = 0; i < 2; ++i) {
    int cid = t + i * 256, d = cid >> 3, c = cid & 7;
    half8 v;
#pragma unroll
    for (int jj = 0; jj < 8; ++jj) v[jj] = L[c * 8 + jj][d];
    *(half8*)(VT + ((size_t)h * HD + d) * NT + n0 + c * 8) = v;
  }
}

// ---------------- flash attention, one block = (head, 128-row Q tile) ----------------
// Bounded scores (|S|<=8) -> no max tracking. Swapped QK^T + key-slot
// permutation -> P stays in registers. 2x q-blocking per wave: each kf/vf
// LDS read feeds 2 MFMAs (LDS-read-bound fix). lsum via MFMA with a
// register-built ones B-frag (l15==0). Reg ping-pong K/V prefetch.
__global__ __launch_bounds__(256, 2) void attn_kernel(const _Float16* __restrict__ Qh,
                                                      const _Float16* __restrict__ Kh,
                                                      const _Float16* __restrict__ VT,
                                                      _Float16* __restrict__ Oh) {
  __shared__ _Float16 Ks[64][72];  // [slot][d], rows permuted by rho
  __shared__ _Float16 Vs[64][72];  // [d][key]
  const int tid = threadIdx.x, lane = tid & 63, w = tid >> 6;
  const int l15 = lane & 15, l4 = lane >> 4;
  // XCD-aware mapping: 512 blocks, heads {2x,2x+1} pinned to XCD x
  int bid = blockIdx.x;
  int s = bid >> 3;                 // [0,64)
  int h = (bid & 7) * 2 + (s >> 5);
  int n0 = (s & 31) * 128;
  half8 qf[2][2];  // [qb][kk], q rows = n0 + w*32 + qb*16 + l15
#pragma unroll
  for (int qb = 0; qb < 2; ++qb)
#pragma unroll
    for (int kk = 0; kk < 2; ++kk)
      qf[qb][kk] = *(const half8*)(Qh + ((size_t)h * NT + n0 + w * 32 + qb * 16 + l15) * HD + kk * 32 + l4 * 8);
  f32x4 acc[2][4] = {};
  f32x4 acc5[2] = {};              // lsum accumulators (col 0 = row-sum)
  half8 of1 = {};                  // ones B-frag: B[idx=0][k]=1 -> l15==0 lanes
  if (l15 == 0) {
#pragma unroll
    for (int j = 0; j < 8; ++j) of1[j] = (_Float16)1.0f;
  }
  // staging geometry: thread covers K rows {gr0, gr1} chunk c; K stored at rho(row)
  const int gr0 = tid >> 3, gr1 = gr0 + 32, c = tid & 7;
  auto rho = [](int g) {
    return (g & 32) | (((g >> 2) & 1) << 4) | (((g >> 3) & 3) << 2) | (g & 3);
  };
  const int pr0 = rho(gr0), pr1 = rho(gr1);
  const _Float16* Kb = Kh + (size_t)h * NT * HD;
  const _Float16* Vb = VT + (size_t)h * HD * NT;
  half8 kA0, kA1, vA0, vA1, kB0, kB1, vB0, vB1;
  auto loadset = [&](int k0, half8& ka, half8& kb, half8& va, half8& vb) {
    ka = *(const half8*)(Kb + (size_t)(k0 + gr0) * HD + c * 8);
    kb = *(const half8*)(Kb + (size_t)(k0 + gr1) * HD + c * 8);
    va = *(const half8*)(Vb + (size_t)gr0 * NT + k0 + c * 8);
    vb = *(const half8*)(Vb + (size_t)gr1 * NT + k0 + c * 8);
  };
  auto storeset = [&](half8 ka, half8 kb, half8 va, half8 vb) {
    *(half8*)&Ks[pr0][c * 8] = ka;
    *(half8*)&Ks[pr1][c * 8] = kb;
    *(half8*)&Vs[gr0][c * 8] = va;
    *(half8*)&Vs[gr1][c * 8] = vb;
  };
  auto compute = [&]() {
    f32x4 sv[2][4] = {};
    __builtin_amdgcn_s_setprio(1);
#pragma unroll
    for (int t = 0; t < 4; ++t) {
      half8 kf0 = *(half8*)&Ks[t * 16 + l15][l4 * 8];
      half8 kf1 = *(half8*)&Ks[t * 16 + l15][32 + l4 * 8];
      sv[0][t] = __builtin_amdgcn_mfma_f32_16x16x32_f16(kf0, qf[0][0], sv[0][t], 0, 0, 0);
      sv[0][t] = __builtin_amdgcn_mfma_f32_16x16x32_f16(kf1, qf[0][1], sv[0][t], 0, 0, 0);
      sv[1][t] = __builtin_amdgcn_mfma_f32_16x16x32_f16(kf0, qf[1][0], sv[1][t], 0, 0, 0);
      sv[1][t] = __builtin_amdgcn_mfma_f32_16x16x32_f16(kf1, qf[1][1], sv[1][t], 0, 0, 0);
    }
    __builtin_amdgcn_s_setprio(0);
    // p = 2^S; pack with v_cvt_pkrtz. pf[kk][j] = e[2kk + (j>>2)][j&3]
    union U { half8 v; half2 p[4]; };
    U u[2][2];
#pragma unroll
    for (int qb = 0; qb < 2; ++qb) {
      float e[4][4];
#pragma unroll
      for (int t = 0; t < 4; ++t)
#pragma unroll
        for (int r = 0; r < 4; ++r) e[t][r] = EXP2(sv[qb][t][r]);
      u[qb][0].p[0] = pk_f16(e[0][0], e[0][1]); u[qb][0].p[1] = pk_f16(e[0][2], e[0][3]);
      u[qb][0].p[2] = pk_f16(e[1][0], e[1][1]); u[qb][0].p[3] = pk_f16(e[1][2], e[1][3]);
      u[qb][1].p[0] = pk_f16(e[2][0], e[2][1]); u[qb][1].p[1] = pk_f16(e[2][2], e[2][3]);
      u[qb][1].p[2] = pk_f16(e[3][0], e[3][1]); u[qb][1].p[3] = pk_f16(e[3][2], e[3][3]);
    }
    __builtin_amdgcn_s_setprio(1);
#pragma unroll
    for (int t = 0; t < 4; ++t) {
      half8 vf0 = *(half8*)&Vs[t * 16 + l15][l4 * 8];
      half8 vf1 = *(half8*)&Vs[t * 16 + l15][32 + l4 * 8];
      acc[0][t] = __builtin_amdgcn_mfma_f32_16x16x32_f16(u[0][0].v, vf0, acc[0][t], 0, 0, 0);
      acc[0][t] = __builtin_amdgcn_mfma_f32_16x16x32_f16(u[0][1].v, vf1, acc[0][t], 0, 0, 0);
      acc[1][t] = __builtin_amdgcn_mfma_f32_16x16x32_f16(u[1][0].v, vf0, acc[1][t], 0, 0, 0);
      acc[1][t] = __builtin_amdgcn_mfma_f32_16x16x32_f16(u[1][1].v, vf1, acc[1][t], 0, 0, 0);
    }
    // lsum: ones-frag B operand, zero LDS traffic
    acc5[0] = __builtin_amdgcn_mfma_f32_16x16x32_f16(u[0][0].v, of1, acc5[0], 0, 0, 0);
    acc5[0] = __builtin_amdgcn_mfma_f32_16x16x32_f16(u[0][1].v, of1, acc5[0], 0, 0, 0);
    acc5[1] = __builtin_amdgcn_mfma_f32_16x16x32_f16(u[1][0].v, of1, acc5[1], 0, 0, 0);
    acc5[1] = __builtin_amdgcn_mfma_f32_16x16x32_f16(u[1][1].v, of1, acc5[1], 0, 0, 0);
    __builtin_amdgcn_s_setprio(0);
  };
  // prologue: tile 0 into set A
  loadset(0, kA0, kA1, vA0, vA1);
  for (int k0 = 0; k0 < NT; k0 += 128) {
    __syncthreads();                       // LDS free (prior reads done)
    storeset(kA0, kA1, vA0, vA1);
    __syncthreads();                       // LDS ready
    loadset(k0 + 64, kB0, kB1, vB0, vB1);  // prefetch next tile (always < NT)
    compute();                             // tile k0
    __syncthreads();
    storeset(kB0, kB1, vB0, vB1);
    __syncthreads();
    if (k0 + 128 < NT) loadset(k0 + 128, kA0, kA1, vA0, vA1);
    compute();                             // tile k0+64
  }
  // lsum for q-row (qb*16 + l4*4+r) sits in acc5[qb][r] of lane (l4, l15=0)
#pragma unroll
  for (int qb = 0; qb < 2; ++qb) {
    float linv[4];
#pragma unroll
    for (int r = 0; r < 4; ++r) linv[r] = 1.0f / __shfl(acc5[qb][r], lane & 48);
#pragma unroll
    for (int t = 0; t < 4; ++t)
#pragma unroll
      for (int r = 0; r < 4; ++r) {
        int row = n0 + w * 32 + qb * 16 + l4 * 4 + r;
        Oh[(size_t)row * CH + h * HD + t * 16 + l15] = (_Float16)(acc[qb][t][r] * linv[r]);
      }
  }
}

extern "C" void kernel_launch(void* const* d_in, const int* in_sizes, int n_in,
                              void* d_out, int out_size, void* d_ws, size_t ws_size,
                              hipStream_t stream) {
  const float* x      = (const float*)d_in[0];
  const int*   coords = (const int*)d_in[1];
  const float* w_qkv  = (const float*)d_in[2];
  const float* w_out  = (const float*)d_in[3];
  const float* gq     = (const float*)d_in[4];
  const float* gk     = (const float*)d_in[5];
  float* out = (float*)d_out;

  char* ws = (char*)d_ws;
  size_t off = 0;
  auto alloc = [&](size_t bytes) { char* p = ws + off; off += bytes; return p; };
  _Float16* xh   = (_Float16*)alloc((size_t)NT * CH * 2);  // x in f16
  _Float16* wqh  = (_Float16*)alloc((size_t)C3 * CH * 2);  // w_qkv f16
  _Float16* woh  = (_Float16*)alloc((size_t)CH * CH * 2);  // w_out f16
  _Float16* qkvh = (_Float16*)alloc((size_t)NT * C3 * 2);  // qkv f16
  _Float16* Qh   = (_Float16*)alloc((size_t)NT * CH * 2);  // [H][N][64], pre-scaled
  _Float16* Kh   = (_Float16*)alloc((size_t)NT * CH * 2);  // [H][N][64]
  _Float16* VTh  = (_Float16*)alloc((size_t)NT * CH * 2);  // [H][64][N]
  _Float16* Oh   = (_Float16*)alloc((size_t)NT * CH * 2);  // attn out [N][C]
  if (off > ws_size) return;  // workspace too small: fail cleanly

  cvt_kernel<<<NT * CH / 4 / 256, 256, 0, stream>>>(x, xh, NT * CH / 4);
  cvt_kernel<<<C3 * CH / 4 / 256, 256, 0, stream>>>(w_qkv, wqh, C3 * CH / 4);
  cvt_kernel<<<CH * CH / 4 / 256, 256, 0, stream>>>(w_out, woh, CH * CH / 4);
  gemm_bt<_Float16><<<dim3(NT / 128, C3 / 128), 256, 0, stream>>>(xh, wqh, qkvh, NT, C3, CH);
  rmsrope_kernel<<<NT * NH / 4, 256, 0, stream>>>(qkvh, coords, gq, gk, Qh, Kh);
  vtrans_kernel<<<dim3(NT / 64, NH), 256, 0, stream>>>(qkvh, VTh);
  attn_kernel<<<NH * (NT / 128), 256, 0, stream>>>(Qh, Kh, VTh, Oh);
  gemm_bt<float><<<dim3(NT / 128, CH / 128), 256, 0, stream>>>(Oh, woh, out, NT, CH, CH);
}